// Round 2
// baseline (384.338 us; speedup 1.0000x reference)
//
#include <hip/hip_runtime.h>
#include <hip/hip_bf16.h>

// CapsModel: B=64 N=32 H=W=16 A=16 K=3 stride=2 -> Ho=Wo=7, M=32, SD=4, D=16
// R18: conv routing rewritten on MFMA (v_mfma_f32_16x16x32_f16).
//   votes[(nkl,a),(d,m)] = sum_x inp[nkl,a,x] w[nkl,x,d,m] is block-diagonal
//   over nkl in K: 4 nkl per 16x16x32 tile (K=(j'*8+x), A zero off-diag,
//   1/4 K-util => ~500 TF effective, vs 103 TF VALU). Per site-pass:
//   72 quads x 8 m-tiles = 576 MFMA. C layout (verified): col=lane&15,
//   row=(lane>>4)*4+reg => lane(hi,c) holds vote[nkl0+hi][m=4t+(c&3)]
//   [a=reg][d=c>>2]; softmax over m = xor4/8 (d-sum) + xor1/2 (m-sum).
//   wTh inner=d*4+x and s_inp inner=a*4+x are already the exact B/A feeds.
//   Pass0 = pure accumulated MFMA. launch_bounds (256,2): ~180 VGPR live
//   (B dbuf 64 + acc 32 + c 32 + vreg 32), must not spill (R17 lesson:
//   WRITE_SIZE is the spill tell - expect it to stay == vout 6.3MB).
// fc routing R16: 4 launches, prev-partial double-buffered. Unchanged.

#define LN_EPS 1e-5f

typedef _Float16 h2 __attribute__((ext_vector_type(2)));
typedef _Float16 half8_t __attribute__((ext_vector_type(8)));
typedef float float4_t __attribute__((ext_vector_type(4)));

__device__ __forceinline__ unsigned packh2(float a, float b) {
    const unsigned short ua = __builtin_bit_cast(unsigned short, (_Float16)a);
    const unsigned short ub = __builtin_bit_cast(unsigned short, (_Float16)b);
    return (unsigned)ua | ((unsigned)ub << 16);
}

// ---------------- weight transposes ----------------
// wTh [288][32][16] f16: row r = n*9+kl; inner idx = d*4+x (x-pairs adjacent).
__global__ __launch_bounds__(256) void transpose_wconv(
    const float* __restrict__ wconv, unsigned short* __restrict__ wTh)
{
    const int i = blockIdx.x * 256 + threadIdx.x;
    if (i < 147456) {
        const int x = i & 3, d = (i >> 2) & 3, mm = (i >> 4) & 31, r = i >> 9;
        const int n = r / 9, kl = r % 9;
        const float v = wconv[((kl * 32 + n) * 16 + x * 4 + d) * 32 + mm];
        wTh[i] = __builtin_bit_cast(unsigned short, (_Float16)v);
    }
}
// wT2b [1568][16][16] fp32: [n][m (pad 10->16, zeros)][x*4+d]
__global__ __launch_bounds__(256) void transpose_wfc(
    const float* __restrict__ wfc, float* __restrict__ wT2b)
{
    const int j = blockIdx.x * 256 + threadIdx.x;
    if (j < 401408) {
        const int xd = j & 15, mm = (j >> 4) & 15, n = j >> 8;
        const int x = xd >> 2, dd = xd & 3;
        wT2b[j] = (mm < 10) ? wfc[((n * 4 + x) * 4 + dd) * 10 + mm] : 0.f;
    }
}
// fused (roomy ws layout)
__global__ __launch_bounds__(256) void transpose_weights(
    const float* __restrict__ wconv, const float* __restrict__ wfc,
    unsigned short* __restrict__ wTh, float* __restrict__ wT2b)
{
    const int blk = blockIdx.x;
    if (blk < 576) {
        const int i = blk * 256 + threadIdx.x;
        if (i < 147456) {
            const int x = i & 3, d = (i >> 2) & 3, mm = (i >> 4) & 31, r = i >> 9;
            const int n = r / 9, kl = r % 9;
            const float v = wconv[((kl * 32 + n) * 16 + x * 4 + d) * 32 + mm];
            wTh[i] = __builtin_bit_cast(unsigned short, (_Float16)v);
        }
    } else {
        const int j = (blk - 576) * 256 + threadIdx.x;
        if (j < 401408) {
            const int xd = j & 15, mm = (j >> 4) & 15, n = j >> 8;
            const int x = xd >> 2, dd = xd & 3;
            wT2b[j] = (mm < 10) ? wfc[((n * 4 + x) * 4 + dd) * 10 + mm] : 0.f;
        }
    }
}

// ---------------- Stage 1: conv routing (MFMA) ----------------
__global__ __launch_bounds__(256, 2) void conv_routing_kernel(
    const float* __restrict__ x,             // [64][32][16][16][16]
    const unsigned short* __restrict__ wTh,  // [288][32][16] f16, inner=d*4+x
    const float* __restrict__ ln1g,
    const float* __restrict__ ln1b,
    const int*   __restrict__ nroute,
    float* __restrict__ vout)                // [64][32][49][16]
{
    __shared__ unsigned short s_inp[289][16];  // row 288 = zeros (A off-diag)
    __shared__ float s_v2[32][16];             // v as [m][d*4+a]
    __shared__ float s_part[4][16][36];        // per-wave partials (pad 36)

    const int tid = threadIdx.x;
    const int wv  = tid >> 6;
    const int l   = tid & 63;
    const int hi  = l >> 4;          // K-block j' == C row-group j == B k-group
    const int c   = l & 15;          // C col = d*4+msub ; A row = j*4+a
    const int msub = l & 3;
    const int dq   = c >> 2;
    const int aj   = c >> 2;         // A-row j
    const int aa   = c & 3;          // A-row a
    const bool partA = (aj == hi);   // block-diagonal participation

    const int site = blockIdx.x;
    const int b = site / 49, hw = site % 49;
    const int h = hw / 7, w = hw % 7;

    // stage inp (coalesced float4 loads, f16 pack); row = n*9+kl, inner a*4+x
    for (int i = tid; i < 1152; i += 256) {    // 288 rows * 4 quads
        const int row = i >> 2, q = i & 3;
        const int n = row / 9, kl = row % 9;
        const int k = kl / 3, lw2 = kl % 3;
        const float4 val = *(const float4*)(
            x + ((((b * 32 + n) * 16 + (2 * h + k)) * 16 + (2 * w + lw2)) * 16 + q * 4));
        uint2 p;
        p.x = packh2(val.x, val.y);
        p.y = packh2(val.z, val.w);
        *(uint2*)(&s_inp[row][q * 4]) = p;
    }
    if (tid < 4) {                             // zero row 288 (32B)
        uint2 z; z.x = 0u; z.y = 0u;
        *(uint2*)(&s_inp[288][tid * 4]) = z;
    }
    __syncthreads();

    const int R = *nroute;
    const int rowBase = wv * 72;               // this wave's 72 nkl rows

    // per-lane invariant addresses
    // A (LDS): participating lanes read s_inp[rowq+aj][aa*4 .. +3] (8B)
    const int aOffPart = aj * 32 + aa * 8;         // bytes within quad
    const int aOffZero = 288 * 32 + aa * 8;        // zero row
    // B (global): half-index = (row'*32 + m)*16 + d*4 ; row' = rowq+hi, m=4t+msub
    const unsigned short* const bpl =
        wTh + ((rowBase + hi) * 32 + msub) * 16 + dq * 4;

    const float4_t z4 = {0.f, 0.f, 0.f, 0.f};

    for (int pass = 0; pass < R; ++pass) {
        float4_t vr[8];
        if (pass) {
#pragma unroll
            for (int t = 0; t < 8; ++t)
                vr[t] = *(const float4_t*)(&s_v2[4 * t + msub][dq * 4]);
        }

        float4_t acc[8];
#pragma unroll
        for (int t = 0; t < 8; ++t) acc[t] = z4;

        // B double buffer; top half of each half8 stays zero (A off-diag too)
        uint4 Bbuf[2][8];
#pragma unroll
        for (int s = 0; s < 2; ++s)
#pragma unroll
            for (int t = 0; t < 8; ++t) {
                Bbuf[s][t].z = 0u; Bbuf[s][t].w = 0u;
            }
#pragma unroll
        for (int t = 0; t < 8; ++t) {          // preload quad 0
            const uint2 bv = *(const uint2*)(bpl + t * 64);
            Bbuf[0][t].x = bv.x; Bbuf[0][t].y = bv.y;
        }

#pragma unroll 2
        for (int q = 0; q < 18; ++q) {
            const int rowq = rowBase + q * 4;
            // A fragment
            const int addrA = partA ? (rowq * 32 + aOffPart) : aOffZero;
            const uint2 av = *(const uint2*)((const char*)(&s_inp[0][0]) + addrA);
            uint4 au; au.x = av.x; au.y = av.y; au.z = 0u; au.w = 0u;
            const half8_t a8 = __builtin_bit_cast(half8_t, au);

            // prefetch next quad's B
            if (q < 17) {
                const unsigned short* bp2 = bpl + (q + 1) * 2048;
#pragma unroll
                for (int t = 0; t < 8; ++t) {
                    const uint2 bv = *(const uint2*)(bp2 + t * 64);
                    Bbuf[(q + 1) & 1][t].x = bv.x;
                    Bbuf[(q + 1) & 1][t].y = bv.y;
                }
            }

            if (pass == 0) {
#pragma unroll
                for (int t = 0; t < 8; ++t) {
                    const half8_t b8 = __builtin_bit_cast(half8_t, Bbuf[q & 1][t]);
                    acc[t] = __builtin_amdgcn_mfma_f32_16x16x32_f16(a8, b8, acc[t], 0, 0, 0);
                }
            } else {
                float4_t ct[8];
#pragma unroll
                for (int t = 0; t < 8; ++t) {
                    const half8_t b8 = __builtin_bit_cast(half8_t, Bbuf[q & 1][t]);
                    ct[t] = __builtin_amdgcn_mfma_f32_16x16x32_f16(a8, b8, z4, 0, 0, 0);
                }
                // logits: lg[nkl=rowq+hi][m=4t+msub] = sum_{a,d} vote * v
                float e[8];
#pragma unroll
                for (int t = 0; t < 8; ++t) {
                    float pt = ct[t][0] * vr[t][0];
                    pt = fmaf(ct[t][1], vr[t][1], pt);
                    pt = fmaf(ct[t][2], vr[t][2], pt);
                    pt = fmaf(ct[t][3], vr[t][3], pt);
                    pt += __shfl_xor(pt, 4, 64);   // sum over d
                    pt += __shfl_xor(pt, 8, 64);
                    e[t] = __expf(pt * 0.25f);
                }
                // softmax over m (8 in-lane tiles x 4 msub lanes)
                float zsum = ((e[0] + e[1]) + (e[2] + e[3]))
                           + ((e[4] + e[5]) + (e[6] + e[7]));
                zsum += __shfl_xor(zsum, 1, 64);
                zsum += __shfl_xor(zsum, 2, 64);
                const float rq = __builtin_amdgcn_rcpf(zsum * (1.f + 1e-10f));
#pragma unroll
                for (int t = 0; t < 8; ++t) {
                    const float qk = e[t] * rq;
                    acc[t] = acc[t] + ct[t] * qk;
                }
            }
        }

        // in-wave reduce over nkl-groups (hi): xor16, xor32
#pragma unroll
        for (int t = 0; t < 8; ++t) {
#pragma unroll
            for (int r = 0; r < 4; ++r) {
                float v0 = acc[t][r];
                v0 += __shfl_xor(v0, 16, 64);
                v0 += __shfl_xor(v0, 32, 64);
                acc[t][r] = v0;
            }
        }
        if (l < 16) {
#pragma unroll
            for (int t = 0; t < 8; ++t)
                *(float4_t*)(&s_part[wv][l][t * 4]) = acc[t];
        }
        __syncthreads();

        // combine 4 waves + LN (128 threads: m = tid>>2, p = d = tid&3)
        if (tid < 128) {
            const int m = tid >> 2, p = tid & 3;
            const int lo = p * 4 + (m & 3), slot = (m >> 2) * 4;
            float4_t xs = *(const float4_t*)(&s_part[0][lo][slot]);
            xs = xs + *(const float4_t*)(&s_part[1][lo][slot]);
            xs = xs + *(const float4_t*)(&s_part[2][lo][slot]);
            xs = xs + *(const float4_t*)(&s_part[3][lo][slot]);
            if (pass == 0) xs = xs * (1.f / 32.f);

            float s0 = (xs[0] + xs[1]) + (xs[2] + xs[3]);
            s0 += __shfl_xor(s0, 1, 64);
            s0 += __shfl_xor(s0, 2, 64);
            const float mu = s0 * (1.f / 16.f);
            float vvar = 0.f;
#pragma unroll
            for (int a = 0; a < 4; ++a) {
                const float d0 = xs[a] - mu;
                vvar = fmaf(d0, d0, vvar);
            }
            vvar += __shfl_xor(vvar, 1, 64);
            vvar += __shfl_xor(vvar, 2, 64);
            const float inv = rsqrtf(vvar * (1.f / 16.f) + LN_EPS);
#pragma unroll
            for (int a = 0; a < 4; ++a)
                s_v2[m][p * 4 + a] = (xs[a] - mu) * inv * ln1g[a * 4 + p] + ln1b[a * 4 + p];
        }
        __syncthreads();
    }

    // vout[m][i = a*4+d] from s_v2[m][d*4+a]
    for (int p = tid; p < 512; p += 256) {
        const int mm = p >> 4, i = p & 15;
        vout[((b * 32 + mm) * 49 + hw) * 16 + i] = s_v2[mm][(i & 3) * 4 + (i >> 2)];
    }
}

// ---------------- Stage 2: FC routing ----------------
// fc_pass: 512 blocks = 64 b x 8 chunks; 256 thr = 16 grp x 16 ml.
// For pass>=1, each block redundantly recomputes its b's u from the
// previous pass's partial (combine+LN in LDS) - no ubuf, no extra launch.
__global__ __launch_bounds__(256, 4) void fc_pass(
    const float* __restrict__ fcin,  // [64][1568][16]
    const float* __restrict__ wT2b,  // [1568][16][16] ([n][ml][x*4+d])
    const float* __restrict__ prev,  // [512][16][16] partial from pass-1 (or null)
    const float* __restrict__ ln2g,
    const float* __restrict__ ln2b,
    const int*   __restrict__ nroute,
    const int    pass,
    float* __restrict__ pout)        // [512][16][16]
{
    __shared__ float s_red[4][16][17];
    __shared__ float s_u[16][17];

    const int R = *nroute;
    if (pass >= R) return;
    const int blk = blockIdx.x;
    const int b = blk >> 3, c = blk & 7;
    const int tid = threadIdx.x;
    const int ml = tid & 15, grp = tid >> 4;
    const int wv = tid >> 6;

    float ur[16];
    if (pass) {
        // inline combine + LN: thread (mlf, ii)
        const int mlf = tid >> 4, ii = tid & 15;
        float s = 0.f;
#pragma unroll
        for (int c2 = 0; c2 < 8; ++c2)
            s += prev[((b * 8 + c2) * 16 + mlf) * 16 + ii];
        if (pass == 1) s *= 0.1f;   // pass-0 output carries the 1/Cls scale
        float mu = s;
#pragma unroll
        for (int off = 8; off >= 1; off >>= 1) mu += __shfl_xor(mu, off, 16);
        mu *= (1.f / 16.f);
        const float d0 = s - mu;
        float var = d0 * d0;
#pragma unroll
        for (int off = 8; off >= 1; off >>= 1) var += __shfl_xor(var, off, 16);
        var *= (1.f / 16.f);
        s_u[mlf][ii] = (s - mu) * rsqrtf(var + LN_EPS) * ln2g[ii] + ln2b[ii];
        __syncthreads();
#pragma unroll
        for (int i = 0; i < 16; ++i) ur[i] = s_u[ml][i];
    }

    const float* fb = fcin + (b * 1568 + c * 196) * 16;
    const float* wb = wT2b + (c * 196 * 16) * 16;

    float un[16];
#pragma unroll
    for (int i = 0; i < 16; ++i) un[i] = 0.f;

    for (int t = 0; t < 13; ++t) {
        const int off = t * 16 + grp;
        if (off >= 196) break;
        float iv[16], wv_[16];
        const float* ip = fb + off * 16;
        const float* wp = wb + (off * 16 + ml) * 16;
#pragma unroll
        for (int q = 0; q < 4; ++q) {
            *(float4*)(&iv[q * 4]) = *(const float4*)(ip + q * 4);
            *(float4*)(&wv_[q * 4]) = *(const float4*)(wp + q * 4);
        }
        float vote[16];
#pragma unroll
        for (int a = 0; a < 4; ++a) {
#pragma unroll
            for (int d = 0; d < 4; ++d) {
                float acc = iv[a * 4 + 0] * wv_[0 + d];
                acc = fmaf(iv[a * 4 + 1], wv_[4 + d], acc);
                acc = fmaf(iv[a * 4 + 2], wv_[8 + d], acc);
                acc = fmaf(iv[a * 4 + 3], wv_[12 + d], acc);
                vote[a * 4 + d] = acc;
            }
        }
        if (pass == 0) {
#pragma unroll
            for (int i = 0; i < 16; ++i) un[i] += vote[i];
        } else {
            float l0 = vote[0] * ur[0], l1 = vote[1] * ur[1];
            float l2 = vote[2] * ur[2], l3 = vote[3] * ur[3];
#pragma unroll
            for (int i = 4; i < 16; i += 4) {
                l0 = fmaf(vote[i + 0], ur[i + 0], l0);
                l1 = fmaf(vote[i + 1], ur[i + 1], l1);
                l2 = fmaf(vote[i + 2], ur[i + 2], l2);
                l3 = fmaf(vote[i + 3], ur[i + 3], l3);
            }
            const float lg = ((l0 + l1) + (l2 + l3)) * 0.25f;
            float e = __expf(lg);
            if (ml >= 10) e = 0.f;
            float sm = e;
#pragma unroll
            for (int off2 = 8; off2 >= 1; off2 >>= 1)
                sm += __shfl_xor(sm, off2, 16);
            const float qk = e * __builtin_amdgcn_rcpf(sm * (1.f + 1e-10f));
#pragma unroll
            for (int i = 0; i < 16; ++i) un[i] = fmaf(qk, vote[i], un[i]);
        }
    }

#pragma unroll
    for (int i = 0; i < 16; ++i) {
        un[i] += __shfl_xor(un[i], 16, 64);
        un[i] += __shfl_xor(un[i], 32, 64);
    }
    if ((tid & 63) < 16) {
#pragma unroll
        for (int i = 0; i < 16; ++i) s_red[wv][ml][i] = un[i];
    }
    __syncthreads();
    {
        const int mlf = tid >> 4, i = tid & 15;
        const float s = s_red[0][mlf][i] + s_red[1][mlf][i]
                      + s_red[2][mlf][i] + s_red[3][mlf][i];
        pout[(blk * 16 + mlf) * 16 + i] = s;
    }
}

// fc_final: combine the last pass's partial, LN, write out.
__global__ __launch_bounds__(256) void fc_final(
    const float* __restrict__ pA,    // partial written by even passes
    const float* __restrict__ pB,    // partial written by odd passes
    const float* __restrict__ ln2g,
    const float* __restrict__ ln2b,
    const int*   __restrict__ nroute,
    float* __restrict__ out)         // [64][10][16]
{
    const int R = *nroute;
    const float* P = ((R - 1) & 1) ? pB : pA;
    const int b = blockIdx.x;
    const int tid = threadIdx.x;
    const int i = tid & 15, ml = tid >> 4;

    float s = 0.f;
#pragma unroll
    for (int c = 0; c < 8; ++c)
        s += P[((b * 8 + c) * 16 + ml) * 16 + i];
    if (R == 1) s *= 0.1f;

    float mu = s;
#pragma unroll
    for (int off = 8; off >= 1; off >>= 1) mu += __shfl_xor(mu, off, 16);
    mu *= (1.f / 16.f);
    const float d0 = s - mu;
    float var = d0 * d0;
#pragma unroll
    for (int off = 8; off >= 1; off >>= 1) var += __shfl_xor(var, off, 16);
    var *= (1.f / 16.f);
    const float r = (s - mu) * rsqrtf(var + LN_EPS) * ln2g[i] + ln2b[i];

    if (ml < 10) out[(b * 10 + ml) * 16 + i] = r;
}

// ---------------- fallback 6-launch fc kernels (proven R14 path) ----------------
__global__ __launch_bounds__(256, 4) void fc_partial(
    const float* __restrict__ fcin, const float* __restrict__ wT2b,
    const float* __restrict__ u, const int* __restrict__ nroute,
    const int pass, float* __restrict__ partial)
{
    __shared__ float s_red[4][16][17];
    const int R = *nroute;
    if (pass >= R) return;
    const int blk = blockIdx.x;
    const int b = blk >> 3, c = blk & 7;
    const int tid = threadIdx.x;
    const int ml = tid & 15, grp = tid >> 4;
    const int wv = tid >> 6;
    const float* fb = fcin + (b * 1568 + c * 196) * 16;
    const float* wb = wT2b + (c * 196 * 16) * 16;

    float un[16];
#pragma unroll
    for (int i = 0; i < 16; ++i) un[i] = 0.f;
    float ur[16];
    if (pass) {
#pragma unroll
        for (int q = 0; q < 4; ++q)
            *(float4*)(&ur[q * 4]) = *(const float4*)(u + (b * 16 + ml) * 16 + q * 4);
    }
    for (int t = 0; t < 13; ++t) {
        const int off = t * 16 + grp;
        if (off >= 196) break;
        float iv[16], wv_[16];
        const float* ip = fb + off * 16;
        const float* wp = wb + (off * 16 + ml) * 16;
#pragma unroll
        for (int q = 0; q < 4; ++q) {
            *(float4*)(&iv[q * 4]) = *(const float4*)(ip + q * 4);
            *(float4*)(&wv_[q * 4]) = *(const float4*)(wp + q * 4);
        }
        float vote[16];
#pragma unroll
        for (int a = 0; a < 4; ++a) {
#pragma unroll
            for (int d = 0; d < 4; ++d) {
                float acc = iv[a * 4 + 0] * wv_[0 + d];
                acc = fmaf(iv[a * 4 + 1], wv_[4 + d], acc);
                acc = fmaf(iv[a * 4 + 2], wv_[8 + d], acc);
                acc = fmaf(iv[a * 4 + 3], wv_[12 + d], acc);
                vote[a * 4 + d] = acc;
            }
        }
        if (pass == 0) {
#pragma unroll
            for (int i = 0; i < 16; ++i) un[i] += vote[i];
        } else {
            float l0 = vote[0] * ur[0], l1 = vote[1] * ur[1];
            float l2 = vote[2] * ur[2], l3 = vote[3] * ur[3];
#pragma unroll
            for (int i = 4; i < 16; i += 4) {
                l0 = fmaf(vote[i + 0], ur[i + 0], l0);
                l1 = fmaf(vote[i + 1], ur[i + 1], l1);
                l2 = fmaf(vote[i + 2], ur[i + 2], l2);
                l3 = fmaf(vote[i + 3], ur[i + 3], l3);
            }
            const float lg = ((l0 + l1) + (l2 + l3)) * 0.25f;
            float e = __expf(lg);
            if (ml >= 10) e = 0.f;
            float sm = e;
#pragma unroll
            for (int off2 = 8; off2 >= 1; off2 >>= 1)
                sm += __shfl_xor(sm, off2, 16);
            const float qk = e * __builtin_amdgcn_rcpf(sm * (1.f + 1e-10f));
#pragma unroll
            for (int i = 0; i < 16; ++i) un[i] = fmaf(qk, vote[i], un[i]);
        }
    }
#pragma unroll
    for (int i = 0; i < 16; ++i) {
        un[i] += __shfl_xor(un[i], 16, 64);
        un[i] += __shfl_xor(un[i], 32, 64);
    }
    if ((tid & 63) < 16) {
#pragma unroll
        for (int i = 0; i < 16; ++i) s_red[wv][ml][i] = un[i];
    }
    __syncthreads();
    {
        const int mlf = tid >> 4, i = tid & 15;
        const float s = s_red[0][mlf][i] + s_red[1][mlf][i]
                      + s_red[2][mlf][i] + s_red[3][mlf][i];
        partial[(blk * 16 + mlf) * 16 + i] = s;
    }
}

__global__ __launch_bounds__(256) void fc_combine(
    const float* __restrict__ partial, const float* __restrict__ ln2g,
    const float* __restrict__ ln2b, const int* __restrict__ nroute,
    const int pass, float* __restrict__ u, float* __restrict__ out)
{
    const int R = *nroute;
    if (pass >= R) return;
    const int b = blockIdx.x;
    const int tid = threadIdx.x;
    const int i = tid & 15, ml = tid >> 4;
    float s = 0.f;
#pragma unroll
    for (int c = 0; c < 8; ++c)
        s += partial[((b * 8 + c) * 16 + ml) * 16 + i];
    if (pass == 0) s *= 0.1f;
    float mu = s;
#pragma unroll
    for (int off = 8; off >= 1; off >>= 1) mu += __shfl_xor(mu, off, 16);
    mu *= (1.f / 16.f);
    const float d0 = s - mu;
    float var = d0 * d0;
#pragma unroll
    for (int off = 8; off >= 1; off >>= 1) var += __shfl_xor(var, off, 16);
    var *= (1.f / 16.f);
    const float r = (s - mu) * rsqrtf(var + LN_EPS) * ln2g[i] + ln2b[i];
    u[(b * 16 + ml) * 16 + i] = r;
    if (pass == R - 1 && ml < 10) out[(b * 10 + ml) * 16 + i] = r;
}

extern "C" void kernel_launch(void* const* d_in, const int* in_sizes, int n_in,
                              void* d_out, int out_size, void* d_ws, size_t ws_size,
                              hipStream_t stream) {
    const float* x     = (const float*)d_in[0];
    const float* wconv = (const float*)d_in[1];
    const float* wfc   = (const float*)d_in[2];
    const float* ln1g  = (const float*)d_in[3];
    const float* ln1b  = (const float*)d_in[4];
    const float* ln2g  = (const float*)d_in[5];
    const float* ln2b  = (const float*)d_in[6];
    const int*   nrt   = (const int*)d_in[7];
    float* out = (float*)d_out;

    float* vout = (float*)d_ws;                                  // 6,422,528 B

    if (ws_size >= 9076736) {
        // new layout: wT2b | pA (wTh aliases its head; dead after conv) | pB
        float* wT2b = (float*)((char*)d_ws + 6422528);           // 1,605,632 B
        float* pA   = (float*)((char*)d_ws + 8028160);           // 524,288 B
        float* pB   = (float*)((char*)d_ws + 8552448);           // 524,288 B
        unsigned short* wTh = (unsigned short*)pA;               // 294,912 B alias

        hipLaunchKernelGGL(transpose_weights, dim3(2144), dim3(256), 0, stream,
                           wconv, wfc, wTh, wT2b);
        hipLaunchKernelGGL(conv_routing_kernel, dim3(3136), dim3(256), 0, stream,
                           x, wTh, ln1g, ln1b, nrt, vout);
        hipLaunchKernelGGL(fc_pass, dim3(512), dim3(256), 0, stream,
                           vout, wT2b, (const float*)nullptr, ln2g, ln2b, nrt, 0, pA);
        hipLaunchKernelGGL(fc_pass, dim3(512), dim3(256), 0, stream,
                           vout, wT2b, (const float*)pA, ln2g, ln2b, nrt, 1, pB);
        hipLaunchKernelGGL(fc_pass, dim3(512), dim3(256), 0, stream,
                           vout, wT2b, (const float*)pB, ln2g, ln2b, nrt, 2, pA);
        hipLaunchKernelGGL(fc_final, dim3(64), dim3(256), 0, stream,
                           pA, pB, ln2g, ln2b, nrt, out);
    } else {
        // fallback: R14's proven tight layout, 6-launch fc
        unsigned short* wTh = (unsigned short*)((char*)d_ws + 6422528);
        float* wT2b    = (float*)((char*)d_ws + 6422528);        // aliases wTh
        float* ubuf    = (float*)((char*)d_ws + 8028160);        // 65,536 B
        float* partial = (float*)((char*)d_ws + 8093696);        // 524,288 B

        hipLaunchKernelGGL(transpose_wconv, dim3(576), dim3(256), 0, stream,
                           wconv, wTh);
        hipLaunchKernelGGL(conv_routing_kernel, dim3(3136), dim3(256), 0, stream,
                           x, wTh, ln1g, ln1b, nrt, vout);
        hipLaunchKernelGGL(transpose_wfc, dim3(1568), dim3(256), 0, stream,
                           wfc, wT2b);
        for (int pass = 0; pass < 3; ++pass) {
            hipLaunchKernelGGL(fc_partial, dim3(512), dim3(256), 0, stream,
                               vout, wT2b, ubuf, nrt, pass, partial);
            hipLaunchKernelGGL(fc_combine, dim3(64), dim3(256), 0, stream,
                               partial, ln2g, ln2b, nrt, pass, ubuf, out);
        }
    }
}